// Round 2
// baseline (1280.447 us; speedup 1.0000x reference)
//
#include <hip/hip_runtime.h>
#include <math.h>

#define C_DIM 64
#define N_B 2
#define SPATIAL (64*64*64)
#define PLANE_SZ (64*64)
#define EPSV 1e-5f

// ---------------- K1: per-channel sum & sumsq ----------------
__global__ __launch_bounds__(256) void k_stats(const float* __restrict__ x,
                                               float* __restrict__ wsf) {
    int c = blockIdx.x >> 4;
    int part = blockIdx.x & 15;
    int tid = threadIdx.x;
    const int per_part = SPATIAL / 16;  // 16384 floats
    float s = 0.f, sq = 0.f;
    for (int n = 0; n < N_B; ++n) {
        const float* base = x + ((size_t)(n * C_DIM + c)) * SPATIAL + (size_t)part * per_part;
        const float4* b4 = (const float4*)base;
        #pragma unroll
        for (int it = 0; it < 16; ++it) {
            float4 v = b4[it * 256 + tid];
            s  += v.x + v.y + v.z + v.w;
            sq += v.x*v.x + v.y*v.y + v.z*v.z + v.w*v.w;
        }
    }
    __shared__ float rs[256], rq[256];
    rs[tid] = s; rq[tid] = sq;
    __syncthreads();
    for (int off = 128; off > 0; off >>= 1) {
        if (tid < off) { rs[tid] += rs[tid+off]; rq[tid] += rq[tid+off]; }
        __syncthreads();
    }
    if (tid == 0) {
        atomicAdd(&wsf[c], rs[0]);
        atomicAdd(&wsf[64 + c], rq[0]);
    }
}

// ---------------- K1b: finalize scale/shift ----------------
__global__ void k_finalize(float* __restrict__ wsf,
                           const float* __restrict__ gamma,
                           const float* __restrict__ beta) {
    int c = threadIdx.x;
    float cnt = (float)(N_B * SPATIAL);
    float mean = wsf[c] / cnt;
    float var = wsf[64 + c] / cnt - mean * mean;
    float sc = gamma[c] * rsqrtf(var + EPSV);
    wsf[128 + c] = sc;
    wsf[192 + c] = beta[c] - mean * sc;
}

// ---------------- K2: fused normalize + depthwise 5x5x5 (pad 2) ----------------
#define K2D 12
#define K2H 12
#define K2W 36
__global__ __launch_bounds__(256) void k_conv5(const float* __restrict__ x,
                                               const float* __restrict__ w0,
                                               const float* __restrict__ b0,
                                               const float* __restrict__ wsf,
                                               float* __restrict__ attn0) {
    __shared__ float sh[K2D * K2H * K2W];
    __shared__ float wt[125];
    int tid = threadIdx.x;
    int tx = tid & 31;
    int ty = tid >> 5;
    int wtile = blockIdx.x;        // 0..1
    int dt = blockIdx.y & 7;       // 0..7
    int ht = blockIdx.y >> 3;      // 0..7
    int nc = blockIdx.z;           // 0..127
    int c = nc & 63;
    int w0i = wtile * 32;
    int h0 = ht * 8;
    int d0 = dt * 8;
    const float* xb = x + (size_t)nc * SPATIAL;
    float sc = wsf[128 + c], shv = wsf[192 + c];
    if (tid < 125) wt[tid] = w0[c * 125 + tid];
    for (int idx = tid; idx < K2D * K2H * K2W; idx += 256) {
        int z = idx / (K2H * K2W);
        int rem = idx - z * (K2H * K2W);
        int y = rem / K2W;
        int xw = rem - y * K2W;
        int gd = d0 - 2 + z, gh = h0 - 2 + y, gw = w0i - 2 + xw;
        float v = 0.f;
        if ((unsigned)gd < 64u && (unsigned)gh < 64u && (unsigned)gw < 64u)
            v = xb[(size_t)gd * PLANE_SZ + gh * 64 + gw] * sc + shv;
        sh[idx] = v;
    }
    __syncthreads();
    float acc[8] = {0,0,0,0,0,0,0,0};
    #pragma unroll
    for (int z = 0; z < 12; ++z) {
        #pragma unroll
        for (int j = 0; j < 5; ++j) {
            #pragma unroll
            for (int k = 0; k < 5; ++k) {
                float v = sh[(z * K2H + (ty + j)) * K2W + tx + k];
                #pragma unroll
                for (int i = 0; i < 5; ++i) {
                    int dz = z - i;
                    if (dz >= 0 && dz < 8)
                        acc[dz] += wt[(i * 5 + j) * 5 + k] * v;
                }
            }
        }
    }
    float bias = b0[c];
    float* ob = attn0 + (size_t)nc * SPATIAL + (size_t)(h0 + ty) * 64 + w0i + tx;
    #pragma unroll
    for (int dz = 0; dz < 8; ++dz)
        ob[(size_t)(d0 + dz) * PLANE_SZ] = acc[dz] + bias;
}

// ---------------- K3 v5: dilated depthwise 7x7x7, dil=3, pad 9 ----------------
// vs v4: software pipeline. Double-buffered LDS plane tile (2 x 2560 floats);
// per stage: (1) issue next plane's 5 global loads into REGISTERS, (2) compute
// current plane from LDS (343 FMA hides the load latency), (3) vmcnt drain +
// mask-mul + ds_write into the OTHER buffer, (4) ONE barrier (was two).
// Write-after-read on buf^1 is safe: the previous stage's end barrier retired
// all its readers. Straight-line templated stages preserved (P compile-time
// -> acc[] statically indexed, stays in VGPRs).
#define ROWS7 26   /* 8 output rows + 18 halo */
#define COLS7 84   /* 82 valid + 2 pad */
#define S7_ELEMS (ROWS7 * COLS7)   /* 2184 */
#define S7_ITERS 5                 /* ceil(2184/512) */
#define S7_BUF 2560                /* per-buffer floats (incl. scribble pad) */

template<int P>
__device__ __forceinline__ void conv7_stage(const float* __restrict__ ab,
                                            const float* __restrict__ wc,
                                            float* __restrict__ sh,
                                            int tid, int hh, int w,
                                            int j0, int rd,
                                            const int (&goff)[S7_ITERS],
                                            const float (&gmsk)[S7_ITERS],
                                            float (&acc)[8]) {
    float* cur = sh + (P & 1) * S7_BUF;
    float* nxt = sh + ((P + 1) & 1) * S7_BUF;
    int mP = j0 - 3 + P;
    int zP = 3 * mP + rd;
    bool zokP = (mP >= 0) && (zP < 64);                 // block-uniform
    int mN = mP + 1;
    int zN = zP + 3;
    bool zokN = (P < 13) && (mN >= 0) && (zN < 64);     // block-uniform

    float r[S7_ITERS];
    if (zokN) {                       // issue prefetch loads FIRST (no wait)
        const float* pb = ab + (size_t)zN * PLANE_SZ;
        #pragma unroll
        for (int k = 0; k < S7_ITERS; ++k)
            r[k] = pb[goff[k]];
    }
    if (zokP) {                       // compute current plane (hides latency)
        #pragma unroll
        for (int v = 0; v < 7; ++v) {
            float val[7];
            int rb = (hh + 3 * v) * COLS7 + w;
            #pragma unroll
            for (int u = 0; u < 7; ++u) val[u] = cur[rb + 3 * u];
            #pragma unroll
            for (int t = 0; t < 7; ++t) {
                const int q = P - t;               // compile-time
                if (q >= 0 && q < 8) {
                    #pragma unroll
                    for (int u = 0; u < 7; ++u)
                        acc[q] = fmaf(wc[t * 49 + v * 7 + u], val[u], acc[q]);
                }
            }
        }
    }
    if (zokN) {                       // drain loads, stage into other buffer
        #pragma unroll
        for (int k = 0; k < S7_ITERS; ++k)
            nxt[k * 512 + tid] = r[k] * gmsk[k];
    }
    __syncthreads();
}

__global__ __launch_bounds__(512, 8) void k_conv7(const float* __restrict__ attn0,
                                                  const float* __restrict__ wsv,
                                                  const float* __restrict__ bs,
                                                  float* __restrict__ attn1) {
    __shared__ float sh[2 * S7_BUF];   // 20 KB double buffer
    int tid = threadIdx.x;
    int w = tid & 63;
    int hh = tid >> 6;             // 0..7  (wave-uniform)
    int ht = blockIdx.x;           // 0..7
    int rd = blockIdx.y % 3;       // residue class in d
    int j0 = (blockIdx.y / 3) * 8; // 0,8,16
    int nc = blockIdx.z;
    int c = nc & 63;
    int h0 = ht * 8;
    int h = h0 + hh;
    const float* ab = attn0 + (size_t)nc * SPATIAL;
    const float* wc = wsv + c * 343;   // block-uniform -> scalar loads

    // ---- hoisted staging geometry: identical for every stage ----
    int goff[S7_ITERS];
    float gmsk[S7_ITERS];
    #pragma unroll
    for (int k = 0; k < S7_ITERS; ++k) {
        int idx = k * 512 + tid;
        int row = idx / COLS7;
        int col = idx - row * COLS7;
        int gy = h0 - 9 + row;
        int gx = col - 9;
        bool valid = (idx < S7_ELEMS) && (col < 82) &&
                     ((unsigned)gy < 64u) && ((unsigned)gx < 64u);
        goff[k] = valid ? (gy * 64 + gx) : 0;   // clamped to a safe address
        gmsk[k] = valid ? 1.f : 0.f;
    }

    // ---- prologue: stage plane for P=0 (if valid) into buf0 ----
    {
        int m0 = j0 - 3;
        int z0 = 3 * m0 + rd;
        if (m0 >= 0 && z0 < 64) {          // block-uniform
            const float* pb = ab + (size_t)z0 * PLANE_SZ;
            #pragma unroll
            for (int k = 0; k < S7_ITERS; ++k)
                sh[k * 512 + tid] = pb[goff[k]] * gmsk[k];
        }
        __syncthreads();
    }

    float acc[8] = {0,0,0,0,0,0,0,0};

    conv7_stage< 0>(ab, wc, sh, tid, hh, w, j0, rd, goff, gmsk, acc);
    conv7_stage< 1>(ab, wc, sh, tid, hh, w, j0, rd, goff, gmsk, acc);
    conv7_stage< 2>(ab, wc, sh, tid, hh, w, j0, rd, goff, gmsk, acc);
    conv7_stage< 3>(ab, wc, sh, tid, hh, w, j0, rd, goff, gmsk, acc);
    conv7_stage< 4>(ab, wc, sh, tid, hh, w, j0, rd, goff, gmsk, acc);
    conv7_stage< 5>(ab, wc, sh, tid, hh, w, j0, rd, goff, gmsk, acc);
    conv7_stage< 6>(ab, wc, sh, tid, hh, w, j0, rd, goff, gmsk, acc);
    conv7_stage< 7>(ab, wc, sh, tid, hh, w, j0, rd, goff, gmsk, acc);
    conv7_stage< 8>(ab, wc, sh, tid, hh, w, j0, rd, goff, gmsk, acc);
    conv7_stage< 9>(ab, wc, sh, tid, hh, w, j0, rd, goff, gmsk, acc);
    conv7_stage<10>(ab, wc, sh, tid, hh, w, j0, rd, goff, gmsk, acc);
    conv7_stage<11>(ab, wc, sh, tid, hh, w, j0, rd, goff, gmsk, acc);
    conv7_stage<12>(ab, wc, sh, tid, hh, w, j0, rd, goff, gmsk, acc);
    conv7_stage<13>(ab, wc, sh, tid, hh, w, j0, rd, goff, gmsk, acc);

    float bias = bs[c];
    float* ob = attn1 + (size_t)nc * SPATIAL + (size_t)h * 64 + w;
    #pragma unroll
    for (int q = 0; q < 8; ++q) {
        int d = 3 * (j0 + q) + rd;
        if (d < 64)
            ob[(size_t)d * PLANE_SZ] = acc[q] + bias;
    }
}

// ---------------- K4: pointwise 1x1x1 (64->64) + bias + gate by x ----------------
__global__ __launch_bounds__(256) void k_pointwise(const float* __restrict__ attn1,
                                                   const float* __restrict__ x,
                                                   const float* __restrict__ w1,
                                                   const float* __restrict__ b1,
                                                   float* __restrict__ out) {
    __shared__ float at[64 * 64];
    int tid = threadIdx.x;
    int sl = tid & 63;
    int cg = __builtin_amdgcn_readfirstlane(tid >> 6);  // 0..3, wave-uniform
    int s0 = blockIdx.x * 64;
    int n = blockIdx.y;
    const float* a_base = attn1 + (size_t)n * C_DIM * SPATIAL + s0;
    #pragma unroll
    for (int it = 0; it < 16; ++it) {
        int idx = it * 256 + tid;
        int row = idx >> 6;
        at[idx] = a_base[(size_t)row * SPATIAL + sl];
    }
    __syncthreads();
    float acc[16];
    #pragma unroll
    for (int j = 0; j < 16; ++j) acc[j] = 0.f;
    for (int ci = 0; ci < 64; ++ci) {
        float va = at[ci * 64 + sl];
        #pragma unroll
        for (int j = 0; j < 16; ++j) {
            int cc = cg * 16 + j;
            acc[j] += w1[cc * 64 + ci] * va;   // wave-uniform -> scalar loads
        }
    }
    const float* xb = x + (size_t)n * C_DIM * SPATIAL + s0;
    float* ob = out + (size_t)n * C_DIM * SPATIAL + s0;
    #pragma unroll
    for (int j = 0; j < 16; ++j) {
        int cc = cg * 16 + j;
        float attn = acc[j] + b1[cc];
        ob[(size_t)cc * SPATIAL + sl] = xb[(size_t)cc * SPATIAL + sl] * attn;
    }
}

extern "C" void kernel_launch(void* const* d_in, const int* in_sizes, int n_in,
                              void* d_out, int out_size, void* d_ws, size_t ws_size,
                              hipStream_t stream) {
    const float* x     = (const float*)d_in[0];
    const float* gamma = (const float*)d_in[1];
    const float* beta  = (const float*)d_in[2];
    const float* w0    = (const float*)d_in[3];
    const float* b0    = (const float*)d_in[4];
    const float* wsv   = (const float*)d_in[5];
    const float* bs    = (const float*)d_in[6];
    const float* w1    = (const float*)d_in[7];
    const float* b1    = (const float*)d_in[8];
    float* out = (float*)d_out;
    float* wsf = (float*)d_ws;
    float* attn1 = wsf + 256;   // 134 MB intermediate in workspace

    hipMemsetAsync(d_ws, 0, 1024, stream);
    k_stats<<<dim3(1024), dim3(256), 0, stream>>>(x, wsf);
    k_finalize<<<dim3(1), dim3(64), 0, stream>>>(wsf, gamma, beta);
    // attn0 lives in d_out; overwritten later by K4 (stream-ordered, safe)
    k_conv5<<<dim3(2, 64, 128), dim3(256), 0, stream>>>(x, w0, b0, wsf, out);
    k_conv7<<<dim3(8, 9, 128), dim3(512), 0, stream>>>(out, wsv, bs, attn1);
    k_pointwise<<<dim3(4096, 2), dim3(256), 0, stream>>>(attn1, x, w1, b1, out);
}

// Round 3
// 1151.937 us; speedup vs baseline: 1.1116x; 1.1116x over previous
//
#include <hip/hip_runtime.h>
#include <math.h>

#define C_DIM 64
#define N_B 2
#define SPATIAL (64*64*64)
#define PLANE_SZ (64*64)
#define EPSV 1e-5f

// ---------------- K1: per-channel sum & sumsq ----------------
__global__ __launch_bounds__(256) void k_stats(const float* __restrict__ x,
                                               float* __restrict__ wsf) {
    int c = blockIdx.x >> 4;
    int part = blockIdx.x & 15;
    int tid = threadIdx.x;
    const int per_part = SPATIAL / 16;  // 16384 floats
    float s = 0.f, sq = 0.f;
    for (int n = 0; n < N_B; ++n) {
        const float* base = x + ((size_t)(n * C_DIM + c)) * SPATIAL + (size_t)part * per_part;
        const float4* b4 = (const float4*)base;
        #pragma unroll
        for (int it = 0; it < 16; ++it) {
            float4 v = b4[it * 256 + tid];
            s  += v.x + v.y + v.z + v.w;
            sq += v.x*v.x + v.y*v.y + v.z*v.z + v.w*v.w;
        }
    }
    __shared__ float rs[256], rq[256];
    rs[tid] = s; rq[tid] = sq;
    __syncthreads();
    for (int off = 128; off > 0; off >>= 1) {
        if (tid < off) { rs[tid] += rs[tid+off]; rq[tid] += rq[tid+off]; }
        __syncthreads();
    }
    if (tid == 0) {
        atomicAdd(&wsf[c], rs[0]);
        atomicAdd(&wsf[64 + c], rq[0]);
    }
}

// ---------------- K1b: finalize scale/shift ----------------
__global__ void k_finalize(float* __restrict__ wsf,
                           const float* __restrict__ gamma,
                           const float* __restrict__ beta) {
    int c = threadIdx.x;
    float cnt = (float)(N_B * SPATIAL);
    float mean = wsf[c] / cnt;
    float var = wsf[64 + c] / cnt - mean * mean;
    float sc = gamma[c] * rsqrtf(var + EPSV);
    wsf[128 + c] = sc;
    wsf[192 + c] = beta[c] - mean * sc;
}

// ---------------- K2: fused normalize + depthwise 5x5x5 (pad 2) ----------------
#define K2D 12
#define K2H 12
#define K2W 36
__global__ __launch_bounds__(256) void k_conv5(const float* __restrict__ x,
                                               const float* __restrict__ w0,
                                               const float* __restrict__ b0,
                                               const float* __restrict__ wsf,
                                               float* __restrict__ attn0) {
    __shared__ float sh[K2D * K2H * K2W];
    __shared__ float wt[125];
    int tid = threadIdx.x;
    int tx = tid & 31;
    int ty = tid >> 5;
    int wtile = blockIdx.x;        // 0..1
    int dt = blockIdx.y & 7;       // 0..7
    int ht = blockIdx.y >> 3;      // 0..7
    int nc = blockIdx.z;           // 0..127
    int c = nc & 63;
    int w0i = wtile * 32;
    int h0 = ht * 8;
    int d0 = dt * 8;
    const float* xb = x + (size_t)nc * SPATIAL;
    float sc = wsf[128 + c], shv = wsf[192 + c];
    if (tid < 125) wt[tid] = w0[c * 125 + tid];
    for (int idx = tid; idx < K2D * K2H * K2W; idx += 256) {
        int z = idx / (K2H * K2W);
        int rem = idx - z * (K2H * K2W);
        int y = rem / K2W;
        int xw = rem - y * K2W;
        int gd = d0 - 2 + z, gh = h0 - 2 + y, gw = w0i - 2 + xw;
        float v = 0.f;
        if ((unsigned)gd < 64u && (unsigned)gh < 64u && (unsigned)gw < 64u)
            v = xb[(size_t)gd * PLANE_SZ + gh * 64 + gw] * sc + shv;
        sh[idx] = v;
    }
    __syncthreads();
    float acc[8] = {0,0,0,0,0,0,0,0};
    #pragma unroll
    for (int z = 0; z < 12; ++z) {
        #pragma unroll
        for (int j = 0; j < 5; ++j) {
            #pragma unroll
            for (int k = 0; k < 5; ++k) {
                float v = sh[(z * K2H + (ty + j)) * K2W + tx + k];
                #pragma unroll
                for (int i = 0; i < 5; ++i) {
                    int dz = z - i;
                    if (dz >= 0 && dz < 8)
                        acc[dz] += wt[(i * 5 + j) * 5 + k] * v;
                }
            }
        }
    }
    float bias = b0[c];
    float* ob = attn0 + (size_t)nc * SPATIAL + (size_t)(h0 + ty) * 64 + w0i + tx;
    #pragma unroll
    for (int dz = 0; dz < 8; ++dz)
        ob[(size_t)(d0 + dz) * PLANE_SZ] = acc[dz] + bias;
}

// ---------------- K3 v6: dilated depthwise 7x7x7, dil=3, pad 9 ----------------
// v5 pipeline, launch bounds relaxed. R2 post-mortem: __launch_bounds__(512,8)
// capped VGPR at 64 and the compiler SPILLED (VGPR_Count=32, WRITE_SIZE
// 131->297 MB scratch stores, FETCH +180 MB scratch reloads). (512,4) gives a
// 128-VGPR cap; the ~60-70 live values (acc[8], r[5], goff/gmsk[10], addrs)
// fit with slack, and at ~64 VGPR the HW still runs 8 waves/SIMD.
// Pipeline: double-buffered LDS plane tile; per stage (1) issue next plane's
// 5 global loads into registers, (2) 343-FMA compute on current buffer hides
// the latency, (3) drain + mask-mul + ds_write into other buffer, (4) ONE
// barrier. Straight-line templated stages keep acc[] statically indexed.
#define ROWS7 26   /* 8 output rows + 18 halo */
#define COLS7 84   /* 82 valid + 2 pad */
#define S7_ELEMS (ROWS7 * COLS7)   /* 2184 */
#define S7_ITERS 5                 /* ceil(2184/512) */
#define S7_BUF 2560                /* per-buffer floats (incl. scribble pad) */

template<int P>
__device__ __forceinline__ void conv7_stage(const float* __restrict__ ab,
                                            const float* __restrict__ wc,
                                            float* __restrict__ sh,
                                            int tid, int hh, int w,
                                            int j0, int rd,
                                            const int (&goff)[S7_ITERS],
                                            const float (&gmsk)[S7_ITERS],
                                            float (&acc)[8]) {
    float* cur = sh + (P & 1) * S7_BUF;
    float* nxt = sh + ((P + 1) & 1) * S7_BUF;
    int mP = j0 - 3 + P;
    int zP = 3 * mP + rd;
    bool zokP = (mP >= 0) && (zP < 64);                 // block-uniform
    int mN = mP + 1;
    int zN = zP + 3;
    bool zokN = (P < 13) && (mN >= 0) && (zN < 64);     // block-uniform

    float r[S7_ITERS];
    if (zokN) {                       // issue prefetch loads FIRST (no wait)
        const float* pb = ab + (size_t)zN * PLANE_SZ;
        #pragma unroll
        for (int k = 0; k < S7_ITERS; ++k)
            r[k] = pb[goff[k]];
    }
    if (zokP) {                       // compute current plane (hides latency)
        #pragma unroll
        for (int v = 0; v < 7; ++v) {
            float val[7];
            int rb = (hh + 3 * v) * COLS7 + w;
            #pragma unroll
            for (int u = 0; u < 7; ++u) val[u] = cur[rb + 3 * u];
            #pragma unroll
            for (int t = 0; t < 7; ++t) {
                const int q = P - t;               // compile-time
                if (q >= 0 && q < 8) {
                    #pragma unroll
                    for (int u = 0; u < 7; ++u)
                        acc[q] = fmaf(wc[t * 49 + v * 7 + u], val[u], acc[q]);
                }
            }
        }
    }
    if (zokN) {                       // drain loads, stage into other buffer
        #pragma unroll
        for (int k = 0; k < S7_ITERS; ++k)
            nxt[k * 512 + tid] = r[k] * gmsk[k];
    }
    __syncthreads();
}

__global__ __launch_bounds__(512, 4) void k_conv7(const float* __restrict__ attn0,
                                                  const float* __restrict__ wsv,
                                                  const float* __restrict__ bs,
                                                  float* __restrict__ attn1) {
    __shared__ float sh[2 * S7_BUF];   // 20 KB double buffer
    int tid = threadIdx.x;
    int w = tid & 63;
    int hh = tid >> 6;             // 0..7  (wave-uniform)
    int ht = blockIdx.x;           // 0..7
    int rd = blockIdx.y % 3;       // residue class in d
    int j0 = (blockIdx.y / 3) * 8; // 0,8,16
    int nc = blockIdx.z;
    int c = nc & 63;
    int h0 = ht * 8;
    int h = h0 + hh;
    const float* ab = attn0 + (size_t)nc * SPATIAL;
    const float* wc = wsv + c * 343;   // block-uniform -> scalar loads

    // ---- hoisted staging geometry: identical for every stage ----
    int goff[S7_ITERS];
    float gmsk[S7_ITERS];
    #pragma unroll
    for (int k = 0; k < S7_ITERS; ++k) {
        int idx = k * 512 + tid;
        int row = idx / COLS7;
        int col = idx - row * COLS7;
        int gy = h0 - 9 + row;
        int gx = col - 9;
        bool valid = (idx < S7_ELEMS) && (col < 82) &&
                     ((unsigned)gy < 64u) && ((unsigned)gx < 64u);
        goff[k] = valid ? (gy * 64 + gx) : 0;   // clamped to a safe address
        gmsk[k] = valid ? 1.f : 0.f;
    }

    // ---- prologue: stage plane for P=0 (if valid) into buf0 ----
    {
        int m0 = j0 - 3;
        int z0 = 3 * m0 + rd;
        if (m0 >= 0 && z0 < 64) {          // block-uniform
            const float* pb = ab + (size_t)z0 * PLANE_SZ;
            #pragma unroll
            for (int k = 0; k < S7_ITERS; ++k)
                sh[k * 512 + tid] = pb[goff[k]] * gmsk[k];
        }
        __syncthreads();
    }

    float acc[8] = {0,0,0,0,0,0,0,0};

    conv7_stage< 0>(ab, wc, sh, tid, hh, w, j0, rd, goff, gmsk, acc);
    conv7_stage< 1>(ab, wc, sh, tid, hh, w, j0, rd, goff, gmsk, acc);
    conv7_stage< 2>(ab, wc, sh, tid, hh, w, j0, rd, goff, gmsk, acc);
    conv7_stage< 3>(ab, wc, sh, tid, hh, w, j0, rd, goff, gmsk, acc);
    conv7_stage< 4>(ab, wc, sh, tid, hh, w, j0, rd, goff, gmsk, acc);
    conv7_stage< 5>(ab, wc, sh, tid, hh, w, j0, rd, goff, gmsk, acc);
    conv7_stage< 6>(ab, wc, sh, tid, hh, w, j0, rd, goff, gmsk, acc);
    conv7_stage< 7>(ab, wc, sh, tid, hh, w, j0, rd, goff, gmsk, acc);
    conv7_stage< 8>(ab, wc, sh, tid, hh, w, j0, rd, goff, gmsk, acc);
    conv7_stage< 9>(ab, wc, sh, tid, hh, w, j0, rd, goff, gmsk, acc);
    conv7_stage<10>(ab, wc, sh, tid, hh, w, j0, rd, goff, gmsk, acc);
    conv7_stage<11>(ab, wc, sh, tid, hh, w, j0, rd, goff, gmsk, acc);
    conv7_stage<12>(ab, wc, sh, tid, hh, w, j0, rd, goff, gmsk, acc);
    conv7_stage<13>(ab, wc, sh, tid, hh, w, j0, rd, goff, gmsk, acc);

    float bias = bs[c];
    float* ob = attn1 + (size_t)nc * SPATIAL + (size_t)h * 64 + w;
    #pragma unroll
    for (int q = 0; q < 8; ++q) {
        int d = 3 * (j0 + q) + rd;
        if (d < 64)
            ob[(size_t)d * PLANE_SZ] = acc[q] + bias;
    }
}

// ---------------- K4: pointwise 1x1x1 (64->64) + bias + gate by x ----------------
__global__ __launch_bounds__(256) void k_pointwise(const float* __restrict__ attn1,
                                                   const float* __restrict__ x,
                                                   const float* __restrict__ w1,
                                                   const float* __restrict__ b1,
                                                   float* __restrict__ out) {
    __shared__ float at[64 * 64];
    int tid = threadIdx.x;
    int sl = tid & 63;
    int cg = __builtin_amdgcn_readfirstlane(tid >> 6);  // 0..3, wave-uniform
    int s0 = blockIdx.x * 64;
    int n = blockIdx.y;
    const float* a_base = attn1 + (size_t)n * C_DIM * SPATIAL + s0;
    #pragma unroll
    for (int it = 0; it < 16; ++it) {
        int idx = it * 256 + tid;
        int row = idx >> 6;
        at[idx] = a_base[(size_t)row * SPATIAL + sl];
    }
    __syncthreads();
    float acc[16];
    #pragma unroll
    for (int j = 0; j < 16; ++j) acc[j] = 0.f;
    for (int ci = 0; ci < 64; ++ci) {
        float va = at[ci * 64 + sl];
        #pragma unroll
        for (int j = 0; j < 16; ++j) {
            int cc = cg * 16 + j;
            acc[j] += w1[cc * 64 + ci] * va;   // wave-uniform -> scalar loads
        }
    }
    const float* xb = x + (size_t)n * C_DIM * SPATIAL + s0;
    float* ob = out + (size_t)n * C_DIM * SPATIAL + s0;
    #pragma unroll
    for (int j = 0; j < 16; ++j) {
        int cc = cg * 16 + j;
        float attn = acc[j] + b1[cc];
        ob[(size_t)cc * SPATIAL + sl] = xb[(size_t)cc * SPATIAL + sl] * attn;
    }
}

extern "C" void kernel_launch(void* const* d_in, const int* in_sizes, int n_in,
                              void* d_out, int out_size, void* d_ws, size_t ws_size,
                              hipStream_t stream) {
    const float* x     = (const float*)d_in[0];
    const float* gamma = (const float*)d_in[1];
    const float* beta  = (const float*)d_in[2];
    const float* w0    = (const float*)d_in[3];
    const float* b0    = (const float*)d_in[4];
    const float* wsv   = (const float*)d_in[5];
    const float* bs    = (const float*)d_in[6];
    const float* w1    = (const float*)d_in[7];
    const float* b1    = (const float*)d_in[8];
    float* out = (float*)d_out;
    float* wsf = (float*)d_ws;
    float* attn1 = wsf + 256;   // 134 MB intermediate in workspace

    hipMemsetAsync(d_ws, 0, 1024, stream);
    k_stats<<<dim3(1024), dim3(256), 0, stream>>>(x, wsf);
    k_finalize<<<dim3(1), dim3(64), 0, stream>>>(wsf, gamma, beta);
    // attn0 lives in d_out; overwritten later by K4 (stream-ordered, safe)
    k_conv5<<<dim3(2, 64, 128), dim3(256), 0, stream>>>(x, w0, b0, wsf, out);
    k_conv7<<<dim3(8, 9, 128), dim3(512), 0, stream>>>(out, wsv, bs, attn1);
    k_pointwise<<<dim3(4096, 2), dim3(256), 0, stream>>>(attn1, x, w1, b1, out);
}